// Round 3
// baseline (157.873 us; speedup 1.0000x reference)
//
#include <hip/hip_runtime.h>
#include <hip/hip_bf16.h>

#define HH 24
#define WW 8
#define HWSZ 192
#define CC 128
#define EPSV 1e-5f

typedef __attribute__((ext_vector_type(8))) short bf16x8;
typedef __attribute__((ext_vector_type(4))) float f32x4;

__device__ __forceinline__ float sigmoidf_(float x) { return 1.0f / (1.0f + expf(-x)); }

__device__ __forceinline__ unsigned short f2bf(float f) {
    unsigned int u = __float_as_uint(f);
    unsigned int r = (u + 0x7fffu + ((u >> 16) & 1u)) >> 16;
    return (unsigned short)r;
}

// ---------------- Kernel 1: fused CBAM, writes bf16 [n][s][c] ----------------
__global__ __launch_bounds__(256) void cbam_kernel(
    const float* __restrict__ prob, const float* __restrict__ gal,
    const float* __restrict__ se_w1, const float* __restrict__ se_w2,
    const float* __restrict__ sa_w, const float* __restrict__ sa_b,
    __hip_bfloat16* __restrict__ pf_t, __hip_bfloat16* __restrict__ gf_t)
{
    __shared__ float mxs[CC], avs[CC], hid[16], cas[CC];
    __shared__ float smx[HWSZ], sav[HWSZ], sas[HWSZ];
    __shared__ float wbuf[2 * 49 * 49];

    int n = blockIdx.x;
    const float* x = (n < 32) ? prob + (size_t)n * CC * HWSZ : gal + (size_t)(n - 32) * CC * HWSZ;
    __hip_bfloat16* dst = (n < 32) ? pf_t + (size_t)n * HWSZ * CC : gf_t + (size_t)(n - 32) * HWSZ * CC;

    int tid = threadIdx.x, l = tid & 63, w = tid >> 6;

    // stage conv weights (49x49x2 floats)
    for (int i = tid; i < 2 * 49 * 49; i += 256) wbuf[i] = sa_w[i];

    // phase 1: per-channel max/mean over 192 spatial positions (wave per 32 channels)
    for (int c = w * 32; c < w * 32 + 32; ++c) {
        const float* row = x + c * HWSZ;
        float a = row[l], b = row[l + 64], d = row[l + 128];
        float mv = fmaxf(a, fmaxf(b, d));
        float sv = a + b + d;
        #pragma unroll
        for (int m = 1; m < 64; m <<= 1) {
            mv = fmaxf(mv, __shfl_xor(mv, m));
            sv += __shfl_xor(sv, m);
        }
        if (l == 0) { mxs[c] = mv; avs[c] = sv * (1.0f / HWSZ); }
    }
    __syncthreads();

    // phase 2: hidden = relu(v @ W1^T), for mx (tid<8) and av (tid 8..15)
    if (tid < 16) {
        int j = tid & 7;
        const float* v = (tid < 8) ? mxs : avs;
        float acc = 0.f;
        for (int c = 0; c < CC; ++c) acc += v[c] * se_w1[j * CC + c];
        hid[tid] = fmaxf(acc, 0.f);
    }
    __syncthreads();

    // phase 3: ca[c] = sigmoid(sum_j (hmx+hav)[j] * W2[c][j])
    if (tid < CC) {
        float acc = 0.f;
        #pragma unroll
        for (int j = 0; j < 8; ++j) acc += (hid[j] + hid[8 + j]) * se_w2[tid * 8 + j];
        cas[tid] = sigmoidf_(acc);
    }
    __syncthreads();

    // phase 4: spatial max/mean over channels of out = x*ca
    if (tid < HWSZ) {
        float mv = -INFINITY, sv = 0.f;
        for (int c = 0; c < CC; ++c) {
            float v = x[c * HWSZ + tid] * cas[c];
            mv = fmaxf(mv, v); sv += v;
        }
        smx[tid] = mv; sav[tid] = sv * (1.0f / CC);
    }
    __syncthreads();

    // phase 5: 49x49 conv, pad=24 -> all-pairs over the 24x8 image
    if (tid < HWSZ) {
        int y = tid >> 3, xx = tid & 7;
        float acc = sa_b[0];
        for (int iy = 0; iy < HH; ++iy) {
            int wy = iy - y + 24;
            const float* w0 = wbuf + wy * 49;
            const float* w1 = wbuf + 2401 + wy * 49;
            #pragma unroll
            for (int ix = 0; ix < WW; ++ix) {
                int wx = ix - xx + 24;
                float s0 = smx[iy * 8 + ix], s1 = sav[iy * 8 + ix];
                acc += s0 * w0[wx] + s1 * w1[wx];
            }
        }
        sas[tid] = sigmoidf_(acc);
    }
    __syncthreads();

    // phase 6: final = x*(1 + ca*sa), store transposed [s][c] as bf16 (packed pairs)
    if (tid < HWSZ) {
        int s = tid;
        float sv = sas[s];
        unsigned int* dst32 = (unsigned int*)(dst + s * CC);
        for (int c = 0; c < CC; c += 2) {
            float v0 = x[c * HWSZ + s] * (1.f + cas[c] * sv);
            float v1 = x[(c + 1) * HWSZ + s] * (1.f + cas[c + 1] * sv);
            unsigned int pk = ((unsigned int)f2bf(v1) << 16) | (unsigned int)f2bf(v0);
            dst32[c >> 1] = pk;
        }
    }
}

// ---------------- Kernel 2: per-(p,g) MFMA matmul + windowed max + scalar ----------------
__global__ __launch_bounds__(256) void score_kernel(
    const __hip_bfloat16* __restrict__ pf_t, const __hip_bfloat16* __restrict__ gf_t,
    const float* __restrict__ bn_g, const float* __restrict__ bn_b,
    const float* __restrict__ bn_m, const float* __restrict__ bn_v,
    const float* __restrict__ fc_w, const float* __restrict__ fc_b,
    const float* __restrict__ lbn_g, const float* __restrict__ lbn_b,
    const float* __restrict__ lbn_m, const float* __restrict__ lbn_v,
    float* __restrict__ out)
{
    __shared__ float M1[24 * HWSZ];   // [hr][s]  max over wr
    __shared__ float M2[HWSZ * 24];   // [r][hs]  max over ws
    __shared__ float red[8];

    int bi = blockIdx.x;
    int p = bi >> 5, g = bi & 31;
    int tid = threadIdx.x, l = tid & 63, w = tid >> 6;

    const __hip_bfloat16* A = gf_t + (size_t)g * HWSZ * CC; // [r][c]
    const __hip_bfloat16* B = pf_t + (size_t)p * HWSZ * CC; // [s][c]

    int row_a = l & 15;
    int koff = (l >> 4) * 8;

    // preload A fragments: 3 r-tiles (48 rows per wave) x 4 k-steps
    bf16x8 afr[3][4];
    #pragma unroll
    for (int rt = 0; rt < 3; ++rt) {
        const __hip_bfloat16* ap = A + (w * 48 + rt * 16 + row_a) * CC + koff;
        #pragma unroll
        for (int ks = 0; ks < 4; ++ks)
            afr[rt][ks] = *(const bf16x8*)(ap + ks * 32);
    }

    for (int st = 0; st < 12; ++st) {
        bf16x8 bfr[4];
        const __hip_bfloat16* bp = B + (st * 16 + row_a) * CC + koff;
        #pragma unroll
        for (int ks = 0; ks < 4; ++ks) bfr[ks] = *(const bf16x8*)(bp + ks * 32);

        #pragma unroll
        for (int rt = 0; rt < 3; ++rt) {
            f32x4 acc = {0.f, 0.f, 0.f, 0.f};
            #pragma unroll
            for (int ks = 0; ks < 4; ++ks)
                acc = __builtin_amdgcn_mfma_f32_16x16x32_bf16(afr[rt][ks], bfr[ks], acc, 0, 0, 0);

            int RT = w * 3 + rt;
            // D layout: row = (l>>4)*4 + reg, col = l&15  (r = RT*16+row, s = st*16+col)

            // M1[hr][s]: max over the 8 wr rows in each hr group
            float mrow = fmaxf(fmaxf(acc[0], acc[1]), fmaxf(acc[2], acc[3]));
            mrow = fmaxf(mrow, __shfl_xor(mrow, 16));
            if (((l >> 4) & 1) == 0)
                M1[(2 * RT + (l >> 5)) * HWSZ + st * 16 + (l & 15)] = mrow;

            // M2[r][hs]: max over 8 cols (ws) within each hs group
            float v0 = acc[0], v1 = acc[1], v2 = acc[2], v3 = acc[3];
            #pragma unroll
            for (int m = 1; m < 8; m <<= 1) {
                v0 = fmaxf(v0, __shfl_xor(v0, m));
                v1 = fmaxf(v1, __shfl_xor(v1, m));
                v2 = fmaxf(v2, __shfl_xor(v2, m));
                v3 = fmaxf(v3, __shfl_xor(v3, m));
            }
            if ((l & 7) == 0) {
                int hs = st * 2 + ((l >> 3) & 1);
                int rbase = RT * 16 + (l >> 4) * 4;
                M2[(rbase + 0) * 24 + hs] = v0;
                M2[(rbase + 1) * 24 + hs] = v1;
                M2[(rbase + 2) * 24 + hs] = v2;
                M2[(rbase + 3) * 24 + hs] = v3;
            }
        }
    }
    __syncthreads();

    // windowed max (6 consecutive h rows, start clip(h-3,0,18)) + fc_w-weighted sum
    float part = 0.f, wpart = 0.f;
    if (tid < HWSZ) {
        int h = tid >> 3;
        int st0 = h - 3; if (st0 < 0) st0 = 0; if (st0 > 18) st0 = 18;
        float v1 = -INFINITY, v2 = -INFINITY;
        #pragma unroll
        for (int i = 0; i < 6; ++i) {
            v1 = fmaxf(v1, M1[(st0 + i) * HWSZ + tid]);
            v2 = fmaxf(v2, M2[tid * 24 + st0 + i]);
        }
        float fw = fc_w[tid];
        part = fw * (v1 + v2);
        wpart = fw;
    }
    #pragma unroll
    for (int m = 1; m < 64; m <<= 1) {
        part  += __shfl_xor(part, m);
        wpart += __shfl_xor(wpart, m);
    }
    if (l == 0) { red[w] = part; red[4 + w] = wpart; }
    __syncthreads();

    if (tid == 0) {
        float total = red[0] + red[1] + red[2] + red[3];
        float Wsum  = red[4] + red[5] + red[6] + red[7];
        float k1 = bn_g[0] * rsqrtf(bn_v[0] + EPSV);
        float Y = k1 * total + 2.f * ((bn_b[0] - k1 * bn_m[0]) * Wsum + fc_b[0]);
        float kl = lbn_g[0] * rsqrtf(lbn_v[0] + EPSV);
        float Z = (Y - lbn_m[0]) * kl + lbn_b[0];
        out[bi] = 1.f / (1.f + expf(-Z));
    }
}

extern "C" void kernel_launch(void* const* d_in, const int* in_sizes, int n_in,
                              void* d_out, int out_size, void* d_ws, size_t ws_size,
                              hipStream_t stream)
{
    const float* prob  = (const float*)d_in[0];
    const float* gal   = (const float*)d_in[1];
    const float* se_w1 = (const float*)d_in[2];
    const float* se_w2 = (const float*)d_in[3];
    const float* sa_w  = (const float*)d_in[4];
    const float* sa_b  = (const float*)d_in[5];
    const float* bn_g  = (const float*)d_in[6];
    const float* bn_b  = (const float*)d_in[7];
    const float* bn_m  = (const float*)d_in[8];
    const float* bn_v  = (const float*)d_in[9];
    const float* fc_w  = (const float*)d_in[10];
    const float* fc_b  = (const float*)d_in[11];
    const float* lbn_g = (const float*)d_in[12];
    const float* lbn_b = (const float*)d_in[13];
    const float* lbn_m = (const float*)d_in[14];
    const float* lbn_v = (const float*)d_in[15];

    __hip_bfloat16* pf_t = (__hip_bfloat16*)d_ws;             // [32][192][128] bf16
    __hip_bfloat16* gf_t = pf_t + (size_t)32 * HWSZ * CC;     // [32][192][128] bf16
    float* out = (float*)d_out;

    cbam_kernel<<<64, 256, 0, stream>>>(prob, gal, se_w1, se_w2, sa_w, sa_b, pf_t, gf_t);
    score_kernel<<<1024, 256, 0, stream>>>(pf_t, gf_t, bn_g, bn_b, bn_m, bn_v,
                                           fc_w, fc_b, lbn_g, lbn_b, lbn_m, lbn_v, out);
}

// Round 4
// 153.576 us; speedup vs baseline: 1.0280x; 1.0280x over previous
//
#include <hip/hip_runtime.h>
#include <hip/hip_bf16.h>

#define HH 24
#define WW 8
#define HWSZ 192
#define CC 128
#define EPSV 1e-5f

#define M1LD 200   // M1 [24][M1LD] bf16
#define M2LD 28    // M2 [192][M2LD] bf16

typedef __attribute__((ext_vector_type(8))) short bf16x8;
typedef __attribute__((ext_vector_type(4))) float f32x4;

__device__ __forceinline__ float sigmoidf_(float x) { return 1.0f / (1.0f + expf(-x)); }

__device__ __forceinline__ unsigned short f2bf(float f) {
    unsigned int u = __float_as_uint(f);
    unsigned int r = (u + 0x7fffu + ((u >> 16) & 1u)) >> 16;
    return (unsigned short)r;
}
__device__ __forceinline__ float bf2f(unsigned short s) {
    return __uint_as_float((unsigned int)s << 16);
}

// ---------------- Kernel 1: fused CBAM, writes bf16 [n][s][c], 512 threads ----------------
__global__ __launch_bounds__(512) void cbam_kernel(
    const float* __restrict__ prob, const float* __restrict__ gal,
    const float* __restrict__ se_w1, const float* __restrict__ se_w2,
    const float* __restrict__ sa_w, const float* __restrict__ sa_b,
    __hip_bfloat16* __restrict__ pf_t, __hip_bfloat16* __restrict__ gf_t)
{
    __shared__ float mxs[CC], avs[CC], hid[16], cas[CC];
    __shared__ float smx2[2 * HWSZ], sav2[2 * HWSZ], sas[HWSZ];
    __shared__ float wbuf[2 * 49 * 49];

    int n = blockIdx.x;
    const float* x = (n < 32) ? prob + (size_t)n * CC * HWSZ : gal + (size_t)(n - 32) * CC * HWSZ;
    __hip_bfloat16* dst = (n < 32) ? pf_t + (size_t)n * HWSZ * CC : gf_t + (size_t)(n - 32) * HWSZ * CC;

    int tid = threadIdx.x, l = tid & 63, w = tid >> 6;

    // stage conv weights (49x49x2 floats)
    for (int i = tid; i < 2 * 49 * 49; i += 512) wbuf[i] = sa_w[i];

    // phase 1: per-channel max/mean over 192 spatial (8 waves x 16 channels)
    for (int i = 0; i < 16; ++i) {
        int c = w * 16 + i;
        const float* row = x + c * HWSZ;
        float a = row[l], b = row[l + 64], d = row[l + 128];
        float mv = fmaxf(a, fmaxf(b, d));
        float sv = a + b + d;
        #pragma unroll
        for (int m = 1; m < 64; m <<= 1) {
            mv = fmaxf(mv, __shfl_xor(mv, m));
            sv += __shfl_xor(sv, m);
        }
        if (l == 0) { mxs[c] = mv; avs[c] = sv * (1.0f / HWSZ); }
    }
    __syncthreads();

    // phase 2: hidden = relu(v @ W1^T); 16 outputs x 16 lanes x 8 channels
    if (tid < 256) {
        int j = tid >> 4, chunk = tid & 15;
        const float* v = (j < 8) ? mxs : avs;
        const float* wrow = se_w1 + (j & 7) * CC + chunk * 8;
        const float* vv = v + chunk * 8;
        float acc = 0.f;
        #pragma unroll
        for (int k = 0; k < 8; ++k) acc += vv[k] * wrow[k];
        #pragma unroll
        for (int m = 1; m < 16; m <<= 1) acc += __shfl_xor(acc, m);
        if (chunk == 0) hid[j] = fmaxf(acc, 0.f);
    }
    __syncthreads();

    // phase 3: ca[c] = sigmoid(sum_j (hmx+hav)[j] * W2[c][j])
    if (tid < CC) {
        float acc = 0.f;
        #pragma unroll
        for (int j = 0; j < 8; ++j) acc += (hid[j] + hid[8 + j]) * se_w2[tid * 8 + j];
        cas[tid] = sigmoidf_(acc);
    }
    __syncthreads();

    // phase 4: spatial max/sum over channels of out = x*ca (2 half-channel passes)
    if (tid < 2 * HWSZ) {
        int s = tid >> 1, half = tid & 1;
        int c0 = half * 64;
        float mv = -INFINITY, sv = 0.f;
        #pragma unroll 4
        for (int k = 0; k < 64; ++k) {
            float v = x[(c0 + k) * HWSZ + s] * cas[c0 + k];
            mv = fmaxf(mv, v); sv += v;
        }
        smx2[half * HWSZ + s] = mv; sav2[half * HWSZ + s] = sv;
    }
    __syncthreads();

    // phase 5: 49x49 conv, pad=24 -> all-pairs over the 24x8 image
    if (tid < HWSZ) {
        int y = tid >> 3, xx = tid & 7;
        float acc = sa_b[0];
        for (int iy = 0; iy < HH; ++iy) {
            int wy = iy - y + 24;
            const float* w0 = wbuf + wy * 49;
            const float* w1 = wbuf + 2401 + wy * 49;
            #pragma unroll
            for (int ix = 0; ix < WW; ++ix) {
                int wx = ix - xx + 24;
                int sp = iy * 8 + ix;
                float s0 = fmaxf(smx2[sp], smx2[HWSZ + sp]);
                float s1 = (sav2[sp] + sav2[HWSZ + sp]) * (1.0f / CC);
                acc += s0 * w0[wx] + s1 * w1[wx];
            }
        }
        sas[tid] = sigmoidf_(acc);
    }
    __syncthreads();

    // phase 6: final = x*(1 + ca*sa), store transposed [s][c] bf16 (2 half-rows/thread)
    if (tid < 2 * HWSZ) {
        int s = tid >> 1, half = tid & 1;
        int c0 = half * 64;
        float sv = sas[s];
        unsigned int* dst32 = (unsigned int*)(dst + s * CC) + half * 32;
        #pragma unroll 4
        for (int k = 0; k < 32; ++k) {
            int c = c0 + 2 * k;
            float v0 = x[c * HWSZ + s] * (1.f + cas[c] * sv);
            float v1 = x[(c + 1) * HWSZ + s] * (1.f + cas[c + 1] * sv);
            dst32[k] = ((unsigned int)f2bf(v1) << 16) | (unsigned int)f2bf(v0);
        }
    }
}

// ---------------- Kernel 2: per-(p,g) MFMA matmul + windowed max, 6 waves ----------------
__global__ __launch_bounds__(384) void score_kernel(
    const __hip_bfloat16* __restrict__ pf_t, const __hip_bfloat16* __restrict__ gf_t,
    const float* __restrict__ bn_g, const float* __restrict__ bn_b,
    const float* __restrict__ bn_m, const float* __restrict__ bn_v,
    const float* __restrict__ fc_w, const float* __restrict__ fc_b,
    const float* __restrict__ lbn_g, const float* __restrict__ lbn_b,
    const float* __restrict__ lbn_m, const float* __restrict__ lbn_v,
    float* __restrict__ out)
{
    __shared__ unsigned short M1b[24 * M1LD];   // [hr][s]  max over wr, bf16
    __shared__ unsigned short M2b[HWSZ * M2LD]; // [r][hs]  max over ws, bf16
    __shared__ float red[6], wred[6];

    int bi = blockIdx.x;
    int p = bi >> 5, g = bi & 31;
    int tid = threadIdx.x, l = tid & 63, w = tid >> 6;   // w in 0..5

    const __hip_bfloat16* A = gf_t + (size_t)g * HWSZ * CC; // [r][c]
    const __hip_bfloat16* B = pf_t + (size_t)p * HWSZ * CC; // [s][c]

    int row_a = l & 15;
    int koff = (l >> 4) * 8;

    // preload A fragments: 2 r-tiles (32 rows per wave) x 4 k-steps = 32 VGPRs
    bf16x8 afr[2][4];
    #pragma unroll
    for (int rt = 0; rt < 2; ++rt) {
        const __hip_bfloat16* ap = A + (w * 32 + rt * 16 + row_a) * CC + koff;
        #pragma unroll
        for (int ks = 0; ks < 4; ++ks)
            afr[rt][ks] = *(const bf16x8*)(ap + ks * 32);
    }

    // B prefetch for st=0
    bf16x8 b0, b1, b2, b3;
    {
        const __hip_bfloat16* bp = B + row_a * CC + koff;
        b0 = *(const bf16x8*)(bp);
        b1 = *(const bf16x8*)(bp + 32);
        b2 = *(const bf16x8*)(bp + 64);
        b3 = *(const bf16x8*)(bp + 96);
    }

    for (int st = 0; st < 12; ++st) {
        bf16x8 n0, n1, n2, n3;
        if (st < 11) {   // issue next tile's loads early; latency hides under MFMA+reduce
            const __hip_bfloat16* bp = B + ((st + 1) * 16 + row_a) * CC + koff;
            n0 = *(const bf16x8*)(bp);
            n1 = *(const bf16x8*)(bp + 32);
            n2 = *(const bf16x8*)(bp + 64);
            n3 = *(const bf16x8*)(bp + 96);
        }

        #pragma unroll
        for (int rt = 0; rt < 2; ++rt) {
            f32x4 acc = {0.f, 0.f, 0.f, 0.f};
            acc = __builtin_amdgcn_mfma_f32_16x16x32_bf16(afr[rt][0], b0, acc, 0, 0, 0);
            acc = __builtin_amdgcn_mfma_f32_16x16x32_bf16(afr[rt][1], b1, acc, 0, 0, 0);
            acc = __builtin_amdgcn_mfma_f32_16x16x32_bf16(afr[rt][2], b2, acc, 0, 0, 0);
            acc = __builtin_amdgcn_mfma_f32_16x16x32_bf16(afr[rt][3], b3, acc, 0, 0, 0);

            int RT = w * 2 + rt;
            // D layout: row = (l>>4)*4 + reg, col = l&15  (r = RT*16+row, s = st*16+col)

            // M1[hr][s]: max over the 8 wr rows in each hr group
            float mrow = fmaxf(fmaxf(acc[0], acc[1]), fmaxf(acc[2], acc[3]));
            mrow = fmaxf(mrow, __shfl_xor(mrow, 16));
            if (((l >> 4) & 1) == 0)
                M1b[(2 * RT + (l >> 5)) * M1LD + st * 16 + (l & 15)] = f2bf(mrow);

            // M2[r][hs]: max over 8 cols (ws) within each hs group
            float v0 = acc[0], v1 = acc[1], v2 = acc[2], v3 = acc[3];
            #pragma unroll
            for (int m = 1; m < 8; m <<= 1) {
                v0 = fmaxf(v0, __shfl_xor(v0, m));
                v1 = fmaxf(v1, __shfl_xor(v1, m));
                v2 = fmaxf(v2, __shfl_xor(v2, m));
                v3 = fmaxf(v3, __shfl_xor(v3, m));
            }
            if ((l & 7) == 0) {
                int hs = st * 2 + ((l >> 3) & 1);
                int rbase = RT * 16 + (l >> 4) * 4;
                M2b[(rbase + 0) * M2LD + hs] = f2bf(v0);
                M2b[(rbase + 1) * M2LD + hs] = f2bf(v1);
                M2b[(rbase + 2) * M2LD + hs] = f2bf(v2);
                M2b[(rbase + 3) * M2LD + hs] = f2bf(v3);
            }
        }
        b0 = n0; b1 = n1; b2 = n2; b3 = n3;
    }
    __syncthreads();

    // windowed max (6 consecutive h rows, start clip(h-3,0,18)) + fc_w-weighted sum
    float part = 0.f, wpart = 0.f;
    if (tid < HWSZ) {
        int h = tid >> 3;
        int st0 = h - 3; if (st0 < 0) st0 = 0; if (st0 > 18) st0 = 18;
        float v1 = -INFINITY, v2 = -INFINITY;
        #pragma unroll
        for (int i = 0; i < 6; ++i) {
            v1 = fmaxf(v1, bf2f(M1b[(st0 + i) * M1LD + tid]));
            v2 = fmaxf(v2, bf2f(M2b[tid * M2LD + st0 + i]));
        }
        float fw = fc_w[tid];
        part = fw * (v1 + v2);
        wpart = fw;
    }
    #pragma unroll
    for (int m = 1; m < 64; m <<= 1) {
        part  += __shfl_xor(part, m);
        wpart += __shfl_xor(wpart, m);
    }
    if (l == 0) { red[w] = part; wred[w] = wpart; }
    __syncthreads();

    if (tid == 0) {
        float total = red[0] + red[1] + red[2] + red[3] + red[4] + red[5];
        float Wsum  = wred[0] + wred[1] + wred[2] + wred[3] + wred[4] + wred[5];
        float k1 = bn_g[0] * rsqrtf(bn_v[0] + EPSV);
        float Y = k1 * total + 2.f * ((bn_b[0] - k1 * bn_m[0]) * Wsum + fc_b[0]);
        float kl = lbn_g[0] * rsqrtf(lbn_v[0] + EPSV);
        float Z = (Y - lbn_m[0]) * kl + lbn_b[0];
        out[bi] = 1.f / (1.f + expf(-Z));
    }
}

extern "C" void kernel_launch(void* const* d_in, const int* in_sizes, int n_in,
                              void* d_out, int out_size, void* d_ws, size_t ws_size,
                              hipStream_t stream)
{
    const float* prob  = (const float*)d_in[0];
    const float* gal   = (const float*)d_in[1];
    const float* se_w1 = (const float*)d_in[2];
    const float* se_w2 = (const float*)d_in[3];
    const float* sa_w  = (const float*)d_in[4];
    const float* sa_b  = (const float*)d_in[5];
    const float* bn_g  = (const float*)d_in[6];
    const float* bn_b  = (const float*)d_in[7];
    const float* bn_m  = (const float*)d_in[8];
    const float* bn_v  = (const float*)d_in[9];
    const float* fc_w  = (const float*)d_in[10];
    const float* fc_b  = (const float*)d_in[11];
    const float* lbn_g = (const float*)d_in[12];
    const float* lbn_b = (const float*)d_in[13];
    const float* lbn_m = (const float*)d_in[14];
    const float* lbn_v = (const float*)d_in[15];

    __hip_bfloat16* pf_t = (__hip_bfloat16*)d_ws;             // [32][192][128] bf16
    __hip_bfloat16* gf_t = pf_t + (size_t)32 * HWSZ * CC;     // [32][192][128] bf16
    float* out = (float*)d_out;

    cbam_kernel<<<64, 512, 0, stream>>>(prob, gal, se_w1, se_w2, sa_w, sa_b, pf_t, gf_t);
    score_kernel<<<1024, 384, 0, stream>>>(pf_t, gf_t, bn_g, bn_b, bn_m, bn_v,
                                           fc_w, fc_b, lbn_g, lbn_b, lbn_m, lbn_v, out);
}